// Round 2
// baseline (403.470 us; speedup 1.0000x reference)
//
#include <hip/hip_runtime.h>
#include <math.h>

#define N_ 16
#define C_ 512
#define L_ 3000
#define A_ 128

// ---------------------------------------------------------------------------
// K1: masked mean per (n,c); "std" = sqrt(clip(mean - mean^2)) (faithful to ref)
// ---------------------------------------------------------------------------
__global__ __launch_bounds__(256) void k_stats(const float* __restrict__ x,
                                               const float* __restrict__ lengths,
                                               float* __restrict__ mg,
                                               float* __restrict__ sg) {
  int n = blockIdx.x >> 9;
  float thr = lengths[n] * (float)L_;
  int T = (int)ceilf(thr); if (T > L_) T = L_;
  const float4* row = (const float4*)(x + (size_t)blockIdx.x * L_);
  int tid = threadIdx.x;
  float sum = 0.f;
  int nf4 = (T + 3) >> 2;
  for (int i = tid; i < nf4; i += 256) {
    float4 v = row[i];
    int l = i * 4;
    if (l + 4 <= T) sum += (v.x + v.y) + (v.z + v.w);
    else {
      if (l     < T) sum += v.x;
      if (l + 1 < T) sum += v.y;
      if (l + 2 < T) sum += v.z;
      if (l + 3 < T) sum += v.w;
    }
  }
  #pragma unroll
  for (int off = 32; off; off >>= 1) sum += __shfl_down(sum, off, 64);
  __shared__ float red[4];
  int wv = tid >> 6, ln = tid & 63;
  if (ln == 0) red[wv] = sum;
  __syncthreads();
  if (tid == 0) {
    float tot = red[0] + red[1] + red[2] + red[3];
    float mean = tot / (float)T;
    mg[blockIdx.x] = mean;
    sg[blockIdx.x] = sqrtf(fmaxf(mean - mean * mean, 1e-12f));
  }
}

// ---------------------------------------------------------------------------
// K1b: per-(n,a) bias d = W1m@mean_g + W1s@std_g + b1 ; BN fold -> scale/shift
// ---------------------------------------------------------------------------
__global__ __launch_bounds__(256) void k_prep(const float* __restrict__ W1,
    const float* __restrict__ b1, const float* __restrict__ gamma,
    const float* __restrict__ beta, const float* __restrict__ bmean,
    const float* __restrict__ bvar, const float* __restrict__ mg,
    const float* __restrict__ sg, float* __restrict__ dba,
    float* __restrict__ scale, float* __restrict__ shift) {
  int n = blockIdx.x;
  __shared__ float sm[C_], ss[C_];
  int tid = threadIdx.x;
  for (int c = tid; c < C_; c += 256) { sm[c] = mg[n * C_ + c]; ss[c] = sg[n * C_ + c]; }
  __syncthreads();
  int wv = tid >> 6, ln = tid & 63;
  for (int a = wv; a < A_; a += 4) {
    const float* wm = W1 + (size_t)a * (3 * C_) + C_;   // mean cols, then std cols
    float acc = 0.f;
    for (int c = ln; c < C_; c += 64) acc += wm[c] * sm[c] + wm[C_ + c] * ss[c];
    #pragma unroll
    for (int off = 32; off; off >>= 1) acc += __shfl_down(acc, off, 64);
    if (ln == 0) dba[n * A_ + a] = acc + b1[a];
  }
  if (n == 0 && tid < A_) {
    float sc = gamma[tid] * rsqrtf(bvar[tid] + 1e-5f);
    scale[tid] = sc;
    shift[tid] = beta[tid] - bmean[tid] * sc;
  }
}

// ---------------------------------------------------------------------------
// K2: h[n,a,l] = tanh( bn( relu( W1x@x + d[n,a] ) ) )
// grid (24 ltiles, 16 n, 2 a-halves), 256 thr, micro-tile 4a x 8l, KC=32
// LDS: 16K + 8.7K = 24.7 KB -> LDS-occupancy 6 blocks/CU
// ---------------------------------------------------------------------------
__global__ __launch_bounds__(256) void k_tdnn(const float* __restrict__ x,
    const float* __restrict__ W1, const float* __restrict__ dba,
    const float* __restrict__ scale, const float* __restrict__ shift,
    const float* __restrict__ lengths, float* __restrict__ h) {
  int lt0 = blockIdx.x * 128;
  int n   = blockIdx.y;
  int ab  = blockIdx.z;          // a0 = ab*64
  float thr = lengths[n] * (float)L_;
  int T = (int)ceilf(thr); if (T > L_) T = L_;
  if (lt0 >= T) return;          // tile fully masked downstream -> never read

  __shared__ float xs[32][128];
  __shared__ float w1s[32][68];
  int tid = threadIdx.x;
  int at = tid >> 4, lt = tid & 15;
  float acc[4][8];
  #pragma unroll
  for (int i = 0; i < 4; i++)
    #pragma unroll
    for (int j = 0; j < 8; j++) acc[i][j] = 0.f;

  for (int c0 = 0; c0 < C_; c0 += 32) {
    __syncthreads();
    { // stage x chunk [32 k][128 l]
      int r  = tid >> 5;
      int c4 = tid & 31;
      int l  = lt0 + c4 * 4;
      #pragma unroll
      for (int p = 0; p < 4; ++p) {
        int k = r + p * 8;
        const float* src = x + (size_t)(n * C_ + c0 + k) * L_ + l;
        float4 v;
        if (l + 3 < L_) v = *(const float4*)src;
        else {
          v.x = (l     < L_) ? src[0] : 0.f;
          v.y = (l + 1 < L_) ? src[1] : 0.f;
          v.z = (l + 2 < L_) ? src[2] : 0.f;
          v.w = (l + 3 < L_) ? src[3] : 0.f;
        }
        *(float4*)&xs[k][c4 * 4] = v;
      }
    }
    { // stage W1 chunk transposed: w1s[k][a_local]
      int al = tid >> 3;
      int k4 = tid & 7;
      #pragma unroll
      for (int p = 0; p < 2; ++p) {
        int a_local = al + p * 32;
        const float* srcw = W1 + (size_t)(ab * 64 + a_local) * (3 * C_) + c0 + k4 * 4;
        float4 v = *(const float4*)srcw;
        w1s[k4 * 4 + 0][a_local] = v.x;
        w1s[k4 * 4 + 1][a_local] = v.y;
        w1s[k4 * 4 + 2][a_local] = v.z;
        w1s[k4 * 4 + 3][a_local] = v.w;
      }
    }
    __syncthreads();
    #pragma unroll 8
    for (int k = 0; k < 32; ++k) {
      float4 wq = *(const float4*)&w1s[k][at * 4];
      float4 x0 = *(const float4*)&xs[k][lt * 8];
      float4 x1 = *(const float4*)&xs[k][lt * 8 + 4];
      float wa[4] = {wq.x, wq.y, wq.z, wq.w};
      float xb[8] = {x0.x, x0.y, x0.z, x0.w, x1.x, x1.y, x1.z, x1.w};
      #pragma unroll
      for (int i = 0; i < 4; i++)
        #pragma unroll
        for (int j = 0; j < 8; j++) acc[i][j] += wa[i] * xb[j];
    }
  }
  // epilogue
  int a0 = ab * 64 + at * 4;
  float db[4], sc[4], sh[4];
  #pragma unroll
  for (int i = 0; i < 4; i++) {
    db[i] = dba[n * A_ + a0 + i];
    sc[i] = scale[a0 + i];
    sh[i] = shift[a0 + i];
  }
  int l = lt0 + lt * 8;
  #pragma unroll
  for (int i = 0; i < 4; i++) {
    float o[8];
    #pragma unroll
    for (int j = 0; j < 8; j++) {
      float v = acc[i][j] + db[i];
      v = fmaxf(v, 0.f);
      v = v * sc[i] + sh[i];
      o[j] = tanhf(v);
    }
    float* dst = h + (size_t)(n * A_ + a0 + i) * L_ + l;
    if (l + 7 < L_) {
      *(float4*)dst       = make_float4(o[0], o[1], o[2], o[3]);
      *(float4*)(dst + 4) = make_float4(o[4], o[5], o[6], o[7]);
    } else {
      for (int j = 0; j < 8; j++) if (l + j < L_) dst[j] = o[j];
    }
  }
}

// ---------------------------------------------------------------------------
// K3a: a = W2@h + b2, masked online softmax over l, weighted sum of x.
// grid (8 ctiles, 16 n, 4 lsegs = 512 blocks = 2/CU), 256 thr,
// micro-tile 4c x 8l, l-tile 128, k staged in two 64-row chunks.
// LDS: hs[64][132]=33.8K + w2t[128][68]=34.8K = 68.6 KB -> 2 blocks/CU
// writes partial (m, s, t) per (n, seg, c)
// ---------------------------------------------------------------------------
__global__ __launch_bounds__(256) void k_attn(const float* __restrict__ h,
    const float* __restrict__ x, const float* __restrict__ W2,
    const float* __restrict__ b2, const float* __restrict__ lengths,
    float* __restrict__ pm, float* __restrict__ ps, float* __restrict__ pt) {
  int c0  = blockIdx.x * 64;
  int n   = blockIdx.y;
  int seg = blockIdx.z;
  __shared__ float hs[64][132];
  __shared__ float w2t[128][68];
  int tid = threadIdx.x;
  int cg = tid >> 4;   // 0..15 -> 4 c each
  int lt = tid & 15;   // 8 l each

  { // stage W2 tile transposed (once, reused across all l-tiles)
    int cl = tid >> 5;
    int k4 = tid & 31;
    #pragma unroll
    for (int p = 0; p < 8; ++p) {
      int c_local = cl + p * 8;
      float4 v = *(const float4*)(W2 + (size_t)(c0 + c_local) * A_ + k4 * 4);
      w2t[k4 * 4 + 0][c_local] = v.x;
      w2t[k4 * 4 + 1][c_local] = v.y;
      w2t[k4 * 4 + 2][c_local] = v.z;
      w2t[k4 * 4 + 3][c_local] = v.w;
    }
  }
  float thr = lengths[n] * (float)L_;
  int T = (int)ceilf(thr); if (T > L_) T = L_;
  float b2v[4], m[4], s[4], t[4];
  #pragma unroll
  for (int i = 0; i < 4; i++) {
    b2v[i] = b2[c0 + cg * 4 + i];
    m[i] = -1e30f; s[i] = 0.f; t[i] = 0.f;
  }
  int lbeg = seg * 768;
  int lend = (lbeg + 768 < L_) ? lbeg + 768 : L_;
  for (int l0 = lbeg; l0 < lend; l0 += 128) {
    if (l0 >= T) break;          // uniform: rest fully masked
    float av[4][8];
    #pragma unroll
    for (int i = 0; i < 4; i++)
      #pragma unroll
      for (int j = 0; j < 8; j++) av[i][j] = 0.f;
    #pragma unroll
    for (int kc = 0; kc < 2; ++kc) {
      __syncthreads();
      { // stage hs [64 k][128 l] for this k-chunk
        int c4 = tid & 31;
        int l  = l0 + c4 * 4;
        #pragma unroll
        for (int p = 0; p < 8; ++p) {
          int k = (tid >> 5) + p * 8;
          const float* src = h + (size_t)(n * A_ + kc * 64 + k) * L_ + l;
          float4 v;
          if (l + 3 < L_) v = *(const float4*)src;
          else {
            v.x = (l     < L_) ? src[0] : 0.f;
            v.y = (l + 1 < L_) ? src[1] : 0.f;
            v.z = (l + 2 < L_) ? src[2] : 0.f;
            v.w = (l + 3 < L_) ? src[3] : 0.f;
          }
          *(float4*)&hs[k][c4 * 4] = v;
        }
      }
      __syncthreads();
      #pragma unroll 8
      for (int k = 0; k < 64; ++k) {
        float4 wq = *(const float4*)&w2t[kc * 64 + k][cg * 4];
        float4 h0 = *(const float4*)&hs[k][lt * 8];
        float4 h1 = *(const float4*)&hs[k][lt * 8 + 4];
        float wa[4] = {wq.x, wq.y, wq.z, wq.w};
        float hb[8] = {h0.x, h0.y, h0.z, h0.w, h1.x, h1.y, h1.z, h1.w};
        #pragma unroll
        for (int i = 0; i < 4; i++)
          #pragma unroll
          for (int j = 0; j < 8; j++) av[i][j] += wa[i] * hb[j];
      }
    }
    // online softmax update
    int lb = l0 + lt * 8;
    #pragma unroll
    for (int i = 0; i < 4; i++) {
      int c = c0 + cg * 4 + i;
      const float* xr = x + (size_t)(n * C_ + c) * L_ + lb;
      float xv[8];
      if (lb + 7 < L_) {
        float4 xa = *(const float4*)xr;
        float4 xb = *(const float4*)(xr + 4);
        xv[0]=xa.x; xv[1]=xa.y; xv[2]=xa.z; xv[3]=xa.w;
        xv[4]=xb.x; xv[5]=xb.y; xv[6]=xb.z; xv[7]=xb.w;
      } else {
        #pragma unroll
        for (int j = 0; j < 8; j++) xv[j] = (lb + j < L_) ? xr[j] : 0.f;
      }
      #pragma unroll
      for (int j = 0; j < 8; j++) {
        int l = lb + j;
        if (l < T) {
          float aval = av[i][j] + b2v[i];
          if (aval > m[i]) {
            float r = __expf(m[i] - aval);
            s[i] *= r; t[i] *= r; m[i] = aval;
          }
          float w = __expf(aval - m[i]);
          s[i] += w; t[i] += w * xv[j];
        }
      }
    }
  }
  // reduce across the 16 l-threads of each cg (stays within a 64-lane wave)
  #pragma unroll
  for (int off = 8; off; off >>= 1) {
    #pragma unroll
    for (int i = 0; i < 4; i++) {
      float om = __shfl_xor(m[i], off, 64);
      float os = __shfl_xor(s[i], off, 64);
      float ot = __shfl_xor(t[i], off, 64);
      float mn = fmaxf(m[i], om);
      float e1 = __expf(m[i] - mn), e2 = __expf(om - mn);
      s[i] = s[i] * e1 + os * e2;
      t[i] = t[i] * e1 + ot * e2;
      m[i] = mn;
    }
  }
  if (lt == 0) {
    #pragma unroll
    for (int i = 0; i < 4; i++) {
      int c = c0 + cg * 4 + i;
      size_t idx = ((size_t)n * 4 + seg) * C_ + c;
      pm[idx] = m[i]; ps[idx] = s[i]; pt[idx] = t[i];
    }
  }
}

// ---------------------------------------------------------------------------
// K3b: combine the 4 l-segments, emit mean and std
// ---------------------------------------------------------------------------
__global__ __launch_bounds__(256) void k_comb(const float* __restrict__ pm,
    const float* __restrict__ ps, const float* __restrict__ pt,
    float* __restrict__ out) {
  int idx = blockIdx.x * 256 + threadIdx.x;
  if (idx >= N_ * C_) return;
  int n = idx >> 9, c = idx & 511;
  float mv[4], sv[4], tv[4];
  float mn = -1e30f;
  #pragma unroll
  for (int g = 0; g < 4; ++g) {
    size_t i = ((size_t)n * 4 + g) * C_ + c;
    mv[g] = pm[i]; sv[g] = ps[i]; tv[g] = pt[i];
    mn = fmaxf(mn, mv[g]);
  }
  float S = 0.f, Tt = 0.f;
  #pragma unroll
  for (int g = 0; g < 4; ++g) {
    float e = __expf(mv[g] - mn);
    S  += sv[g] * e;
    Tt += tv[g] * e;
  }
  float mean = Tt / S;
  out[n * 1024 + c]       = mean;
  out[n * 1024 + 512 + c] = sqrtf(fmaxf(mean - mean * mean, 1e-12f));
}

// ---------------------------------------------------------------------------
extern "C" void kernel_launch(void* const* d_in, const int* in_sizes, int n_in,
                              void* d_out, int out_size, void* d_ws, size_t ws_size,
                              hipStream_t stream) {
  const float* x       = (const float*)d_in[0];
  const float* lengths = (const float*)d_in[1];
  const float* W1      = (const float*)d_in[2];
  const float* b1      = (const float*)d_in[3];
  const float* gamma   = (const float*)d_in[4];
  const float* beta    = (const float*)d_in[5];
  const float* bmean   = (const float*)d_in[6];
  const float* bvar    = (const float*)d_in[7];
  const float* W2      = (const float*)d_in[8];
  const float* b2      = (const float*)d_in[9];
  float* out = (float*)d_out;

  float* w     = (float*)d_ws;
  float* hbuf  = w;                       // 16*128*3000 = 6,144,000
  float* mg    = w + 6144000;             // 8192
  float* sg    = mg + 8192;               // 8192
  float* dba   = sg + 8192;               // 2048
  float* scale = dba + 2048;              // 128
  float* shift = scale + 128;             // 128
  float* pm    = shift + 128;             // 16*4*512 = 32768
  float* ps    = pm + 32768;              // 32768
  float* pt    = ps + 32768;              // 32768

  k_stats<<<dim3(N_ * C_), 256, 0, stream>>>(x, lengths, mg, sg);
  k_prep<<<dim3(N_), 256, 0, stream>>>(W1, b1, gamma, beta, bmean, bvar,
                                       mg, sg, dba, scale, shift);
  k_tdnn<<<dim3(24, N_, 2), 256, 0, stream>>>(x, W1, dba, scale, shift,
                                              lengths, hbuf);
  k_attn<<<dim3(8, N_, 4), 256, 0, stream>>>(hbuf, x, W2, b2, lengths,
                                             pm, ps, pt);
  k_comb<<<dim3(32), 256, 0, stream>>>(pm, ps, pt, out);
}

// Round 6
// 343.374 us; speedup vs baseline: 1.1750x; 1.1750x over previous
//
#include <hip/hip_runtime.h>
#include <math.h>

#define N_ 16
#define C_ 512
#define L_ 3000
#define LP_ 3072   // L padded to a multiple of 128
#define A_ 128
#define SEG_ 8     // l-segments in k_attn (384 l each)

typedef _Float16 f16;
typedef __attribute__((ext_vector_type(8))) _Float16 f16x8;
typedef __attribute__((ext_vector_type(4))) _Float16 f16x4;
typedef __attribute__((ext_vector_type(4))) float f32x4;

// ---------------------------------------------------------------------------
// K1: masked mean per (n,c); "std" = sqrt(clip(mean - mean^2)) (faithful to ref:
// var_like = sum(m*(x - mean^2)) = mean - mean^2 since weights sum to 1)
// ---------------------------------------------------------------------------
__global__ __launch_bounds__(256) void k_stats(const float* __restrict__ x,
                                               const float* __restrict__ lengths,
                                               float* __restrict__ mg,
                                               float* __restrict__ sg) {
  int n = blockIdx.x >> 9;
  float thr = lengths[n] * (float)L_;
  int T = (int)ceilf(thr); if (T > L_) T = L_;
  const float4* row = (const float4*)(x + (size_t)blockIdx.x * L_);
  int tid = threadIdx.x;
  float sum = 0.f;
  int nf4 = (T + 3) >> 2;
  for (int i = tid; i < nf4; i += 256) {
    float4 v = row[i];
    int l = i * 4;
    if (l + 4 <= T) sum += (v.x + v.y) + (v.z + v.w);
    else {
      if (l     < T) sum += v.x;
      if (l + 1 < T) sum += v.y;
      if (l + 2 < T) sum += v.z;
      if (l + 3 < T) sum += v.w;
    }
  }
  #pragma unroll
  for (int off = 32; off; off >>= 1) sum += __shfl_down(sum, off, 64);
  __shared__ float red[4];
  int wv = tid >> 6, ln = tid & 63;
  if (ln == 0) red[wv] = sum;
  __syncthreads();
  if (tid == 0) {
    float tot = red[0] + red[1] + red[2] + red[3];
    float mean = tot / (float)T;
    mg[blockIdx.x] = mean;
    sg[blockIdx.x] = sqrtf(fmaxf(mean - mean * mean, 1e-12f));
  }
}

// ---------------------------------------------------------------------------
// K1b: per-(n,a) bias d = W1m@mean_g + W1s@std_g + b1 ; BN fold;
//      cast W1x -> W1h [128][512] f16, W2 -> W2h [512][128] f16
// ---------------------------------------------------------------------------
__global__ __launch_bounds__(256) void k_prep(const float* __restrict__ W1,
    const float* __restrict__ b1, const float* __restrict__ gamma,
    const float* __restrict__ beta, const float* __restrict__ bmean,
    const float* __restrict__ bvar, const float* __restrict__ W2,
    const float* __restrict__ mg, const float* __restrict__ sg,
    float* __restrict__ dba, float* __restrict__ scale, float* __restrict__ shift,
    f16* __restrict__ W1h, f16* __restrict__ W2h) {
  int n = blockIdx.x;
  __shared__ float sm[C_], ss[C_];
  int tid = threadIdx.x;
  for (int c = tid; c < C_; c += 256) { sm[c] = mg[n * C_ + c]; ss[c] = sg[n * C_ + c]; }
  __syncthreads();
  int wv = tid >> 6, ln = tid & 63;
  for (int a = wv; a < A_; a += 4) {
    const float* wm = W1 + (size_t)a * (3 * C_) + C_;   // mean cols, then std cols
    float acc = 0.f;
    for (int c = ln; c < C_; c += 64) acc += wm[c] * sm[c] + wm[C_ + c] * ss[c];
    #pragma unroll
    for (int off = 32; off; off >>= 1) acc += __shfl_down(acc, off, 64);
    if (ln == 0) dba[n * A_ + a] = acc + b1[a];
  }
  // weight casts: 65536 elements each, split over the 16 blocks
  int base = n * 4096;
  for (int i = tid; i < 4096; i += 256) {
    int idx = base + i;
    int a = idx >> 9, c = idx & 511;
    W1h[idx] = (f16)W1[(size_t)a * (3 * C_) + c];  // x-columns only
    W2h[idx] = (f16)W2[idx];                       // [512][128] contiguous
  }
  if (n == 0 && tid < A_) {
    float sc = gamma[tid] * rsqrtf(bvar[tid] + 1e-5f);
    scale[tid] = sc;
    shift[tid] = beta[tid] - bmean[tid] * sc;
  }
}

// ---------------------------------------------------------------------------
// K2: MFMA GEMM1 with fused transpose-cast load:
//     ht[n][l][a] = tanh(bn(relu(W1h @ x^T + dba)))   (f16 out, [l][a] layout)
// grid (24 ltiles, 16 n), 256 thr = 4 waves in 2x2 (a-half x l-half)
// BM=128(a) BN=128(l) BK=64(c); LDS rows padded to 72 f16 (balanced banks)
// LDS 36.9 KB -> 4 blocks/CU capacity.
// ---------------------------------------------------------------------------
__global__ __launch_bounds__(256) void k_tdnn(const float* __restrict__ x,
    const f16* __restrict__ W1h, const float* __restrict__ dba,
    const float* __restrict__ scale, const float* __restrict__ shift,
    const float* __restrict__ lengths, f16* __restrict__ ht) {
  int lt0 = blockIdx.x * 128;
  int n   = blockIdx.y;
  float thr = lengths[n] * (float)L_;
  int T = (int)ceilf(thr); if (T > L_) T = L_;
  if (lt0 >= T) return;            // fully masked downstream, never read

  __shared__ __align__(16) f16 w1s[128][72];
  __shared__ __align__(16) f16 xts[128][72];
  int tid = threadIdx.x;
  int wid = tid >> 6, lane = tid & 63;
  int wr = wid >> 1, wc = wid & 1;   // wave a-half, l-half
  int fr = lane & 15, fq = lane >> 4;

  f32x4 acc[4][4];
  #pragma unroll
  for (int mi = 0; mi < 4; ++mi)
    #pragma unroll
    for (int ni = 0; ni < 4; ++ni) { f32x4 z = {0.f,0.f,0.f,0.f}; acc[mi][ni] = z; }

  // staging splits
  int tl  = tid & 127;             // l-local row for x-transpose staging
  int tc8 = tid >> 7;              // 0..1 -> c-chunk parity
  bool lok = (lt0 + tl) < L_;
  const float* xbase = x + (size_t)n * C_ * L_ + lt0 + tl;
  int wrow = tid >> 3;             // 0..31 row base for W1h staging
  int wch  = tid & 7;              // 0..7 chunk

  for (int c0 = 0; c0 < C_; c0 += 64) {
    __syncthreads();
    // stage xts[l][c] f16 from x[c][l] fp32 (coalesced along l per c)
    #pragma unroll
    for (int it = 0; it < 4; ++it) {
      int c8 = tc8 + it * 2;                  // 0..7
      int cg = c0 + c8 * 8;
      f16x8 pack;
      #pragma unroll
      for (int j = 0; j < 8; ++j) {
        float v = lok ? xbase[(size_t)(cg + j) * L_] : 0.f;
        pack[j] = (f16)v;
      }
      *(f16x8*)&xts[tl][c8 * 8] = pack;
    }
    // stage w1s[a][c] from W1h
    #pragma unroll
    for (int it = 0; it < 4; ++it) {
      int r = wrow + it * 32;
      *(f16x8*)&w1s[r][wch * 8] =
          *(const f16x8*)(W1h + (size_t)r * C_ + c0 + wch * 8);
    }
    __syncthreads();
    #pragma unroll
    for (int ks = 0; ks < 2; ++ks) {
      f16x8 af[4];
      #pragma unroll
      for (int mi = 0; mi < 4; ++mi)
        af[mi] = *(const f16x8*)&w1s[wr * 64 + mi * 16 + fr][ks * 32 + fq * 8];
      #pragma unroll
      for (int ni = 0; ni < 4; ++ni) {
        f16x8 bfv = *(const f16x8*)&xts[wc * 64 + ni * 16 + fr][ks * 32 + fq * 8];
        #pragma unroll
        for (int mi = 0; mi < 4; ++mi)
          acc[mi][ni] = __builtin_amdgcn_mfma_f32_16x16x32_f16(af[mi], bfv, acc[mi][ni], 0, 0, 0);
      }
    }
  }
  // epilogue: D layout col(lane&15)=l, row((lane>>4)*4+reg)=a
  #pragma unroll
  for (int mi = 0; mi < 4; ++mi) {
    int a0 = wr * 64 + mi * 16 + fq * 4;
    f32x4 dbv = *(const f32x4*)(dba + n * A_ + a0);
    f32x4 scv = *(const f32x4*)(scale + a0);
    f32x4 shv = *(const f32x4*)(shift + a0);
    #pragma unroll
    for (int ni = 0; ni < 4; ++ni) {
      int l = lt0 + wc * 64 + ni * 16 + fr;
      f16x4 pack;
      #pragma unroll
      for (int r = 0; r < 4; ++r) {
        float v = acc[mi][ni][r] + dbv[r];
        v = fmaxf(v, 0.f) * scv[r] + shv[r];
        pack[r] = (f16)tanhf(v);
      }
      *(f16x4*)(ht + ((size_t)n * LP_ + l) * A_ + a0) = pack;
    }
  }
}

// ---------------------------------------------------------------------------
// K3a: MFMA GEMM2 scores = W2h@ht^T + b2, fused masked online softmax + sum(w*x)
// grid (8 cb, 16 n, 8 seg) = 1024 blocks, 256 thr = 4 waves; wave w owns 16 c.
// K=128(a), l-tile 128, 3 tiles/seg; LDS hts rows padded to 136 (34.8 KB).
// ---------------------------------------------------------------------------
__global__ __launch_bounds__(256) void k_attn(const f16* __restrict__ ht,
    const float* __restrict__ x, const f16* __restrict__ W2h,
    const float* __restrict__ b2, const float* __restrict__ lengths,
    float* __restrict__ pm, float* __restrict__ ps, float* __restrict__ pt) {
  int cb = blockIdx.x * 64;
  int n  = blockIdx.y;
  int seg = blockIdx.z;
  __shared__ __align__(16) f16 hts[128][136];
  int tid = threadIdx.x, wid = tid >> 6, lane = tid & 63;
  int fr = lane & 15, fq = lane >> 4;

  // A-fragments of W2 (const per block): c = cb + wid*16 + fr, k = kk*32+fq*8
  f16x8 af[4];
  #pragma unroll
  for (int kk = 0; kk < 4; ++kk)
    af[kk] = *(const f16x8*)(W2h + (size_t)(cb + wid * 16 + fr) * A_ + kk * 32 + fq * 8);

  float thr = lengths[n] * (float)L_;
  int T = (int)ceilf(thr); if (T > L_) T = L_;
  int cme = cb + wid * 16 + fq * 4;          // this lane's 4 c rows
  f32x4 b2v = *(const f32x4*)(b2 + cme);
  const float* xrow[4];
  #pragma unroll
  for (int r = 0; r < 4; ++r) xrow[r] = x + ((size_t)n * C_ + cme + r) * L_;
  float m[4], s[4], t[4];
  #pragma unroll
  for (int r = 0; r < 4; ++r) { m[r] = -1e30f; s[r] = 0.f; t[r] = 0.f; }

  int lbeg = seg * 384;
  int lend = (lbeg + 384 < L_) ? lbeg + 384 : L_;
  int sc16 = tid & 15, sr = tid >> 4;
  for (int l0 = lbeg; l0 < lend; l0 += 128) {
    if (l0 >= T) break;                       // uniform per block
    __syncthreads();
    #pragma unroll
    for (int p = 0; p < 8; ++p) {
      int r = sr + p * 16;
      *(f16x8*)&hts[r][sc16 * 8] =
          *(const f16x8*)(ht + ((size_t)n * LP_ + l0 + r) * A_ + sc16 * 8);
    }
    __syncthreads();
    #pragma unroll
    for (int ni = 0; ni < 8; ++ni) {
      f32x4 acc = {0.f, 0.f, 0.f, 0.f};
      #pragma unroll
      for (int kk = 0; kk < 4; ++kk) {
        f16x8 bfv = *(const f16x8*)&hts[ni * 16 + fr][kk * 32 + fq * 8];
        acc = __builtin_amdgcn_mfma_f32_16x16x32_f16(af[kk], bfv, acc, 0, 0, 0);
      }
      int l = l0 + ni * 16 + fr;
      bool live = l < T;
      #pragma unroll
      for (int r = 0; r < 4; ++r) {
        float aval = live ? (acc[r] + b2v[r]) : -1e30f;
        float mn = fmaxf(m[r], aval);
        float eo = __expf(m[r] - mn);
        float w  = live ? __expf(aval - mn) : 0.f;
        float xv = live ? xrow[r][l] : 0.f;
        s[r] = s[r] * eo + w;
        t[r] = t[r] * eo + w * xv;
        m[r] = mn;
      }
    }
  }
  // reduce across the 16 l-lanes (fr) of each row group (within the wave)
  #pragma unroll
  for (int off = 8; off; off >>= 1) {
    #pragma unroll
    for (int r = 0; r < 4; ++r) {
      float om = __shfl_xor(m[r], off, 64);
      float os = __shfl_xor(s[r], off, 64);
      float ot = __shfl_xor(t[r], off, 64);
      float mn = fmaxf(m[r], om);
      float e1 = __expf(m[r] - mn), e2 = __expf(om - mn);
      s[r] = s[r] * e1 + os * e2;
      t[r] = t[r] * e1 + ot * e2;
      m[r] = mn;
    }
  }
  if (fr == 0) {
    #pragma unroll
    for (int r = 0; r < 4; ++r) {
      size_t idx = ((size_t)n * SEG_ + seg) * C_ + cme + r;
      pm[idx] = m[r]; ps[idx] = s[r]; pt[idx] = t[r];
    }
  }
}

// ---------------------------------------------------------------------------
// K3b: combine the 8 l-segments, emit mean and std
// ---------------------------------------------------------------------------
__global__ __launch_bounds__(256) void k_comb(const float* __restrict__ pm,
    const float* __restrict__ ps, const float* __restrict__ pt,
    float* __restrict__ out) {
  int idx = blockIdx.x * 256 + threadIdx.x;
  if (idx >= N_ * C_) return;
  int n = idx >> 9, c = idx & 511;
  float mn = -1e30f;
  #pragma unroll
  for (int g = 0; g < SEG_; ++g) mn = fmaxf(mn, pm[((size_t)n * SEG_ + g) * C_ + c]);
  float S = 0.f, Tt = 0.f;
  #pragma unroll
  for (int g = 0; g < SEG_; ++g) {
    size_t i = ((size_t)n * SEG_ + g) * C_ + c;
    float e = __expf(pm[i] - mn);
    S  += ps[i] * e;
    Tt += pt[i] * e;
  }
  float mean = Tt / S;
  out[n * 1024 + c]       = mean;
  out[n * 1024 + 512 + c] = sqrtf(fmaxf(mean - mean * mean, 1e-12f));
}

// ---------------------------------------------------------------------------
extern "C" void kernel_launch(void* const* d_in, const int* in_sizes, int n_in,
                              void* d_out, int out_size, void* d_ws, size_t ws_size,
                              hipStream_t stream) {
  const float* x       = (const float*)d_in[0];
  const float* lengths = (const float*)d_in[1];
  const float* W1      = (const float*)d_in[2];
  const float* b1      = (const float*)d_in[3];
  const float* gamma   = (const float*)d_in[4];
  const float* beta    = (const float*)d_in[5];
  const float* bmean   = (const float*)d_in[6];
  const float* bvar    = (const float*)d_in[7];
  const float* W2      = (const float*)d_in[8];
  const float* b2      = (const float*)d_in[9];
  float* out = (float*)d_out;

  // ws usage: ~13.6 MB total (validated budget was ~25 MB in round 2)
  char* w = (char*)d_ws;
  f16* ht    = (f16*)w;    w += (size_t)N_ * LP_ * A_ * 2;   // 12,582,912 B
  f16* W1h   = (f16*)w;    w += (size_t)A_ * C_ * 2;         // 131,072 B
  f16* W2h   = (f16*)w;    w += (size_t)C_ * A_ * 2;         // 131,072 B
  float* mg  = (float*)w;  w += (size_t)N_ * C_ * 4;
  float* sg  = (float*)w;  w += (size_t)N_ * C_ * 4;
  float* dba = (float*)w;  w += (size_t)N_ * A_ * 4;
  float* scale = (float*)w; w += 512;
  float* shift = (float*)w; w += 512;
  float* pm  = (float*)w;  w += (size_t)N_ * SEG_ * C_ * 4;  // 262,144 B
  float* ps  = (float*)w;  w += (size_t)N_ * SEG_ * C_ * 4;
  float* pt  = (float*)w;

  k_stats<<<dim3(N_ * C_), 256, 0, stream>>>(x, lengths, mg, sg);
  k_prep <<<dim3(N_), 256, 0, stream>>>(W1, b1, gamma, beta, bmean, bvar, W2,
                                        mg, sg, dba, scale, shift, W1h, W2h);
  k_tdnn <<<dim3(24, N_), 256, 0, stream>>>(x, W1h, dba, scale, shift, lengths, ht);
  k_attn <<<dim3(8, N_, SEG_), 256, 0, stream>>>(ht, x, W2h, b2, lengths, pm, ps, pt);
  k_comb <<<dim3(32), 256, 0, stream>>>(pm, ps, pt, out);
}

// Round 7
// 254.175 us; speedup vs baseline: 1.5874x; 1.3509x over previous
//
#include <hip/hip_runtime.h>
#include <math.h>

#define N_ 16
#define C_ 512
#define L_ 3000
#define LP_ 3072   // L padded to a multiple of 128
#define A_ 128
#define SEG_ 8     // l-segments in k_attn (384 l each)

typedef _Float16 f16;
typedef __attribute__((ext_vector_type(8))) _Float16 f16x8;
typedef __attribute__((ext_vector_type(4))) _Float16 f16x4;
typedef __attribute__((ext_vector_type(4))) float f32x4;

// ===========================================================================
// FAST PATH (needs ~61 MiB ws): k_cast -> k_prep2 -> k_tdnn_f -> k_attn2 -> k_comb
// ===========================================================================

// ---------------------------------------------------------------------------
// k_cast: transpose+cast x[n][c][l] fp32 -> xt[n][l][c] f16 (zero-pad l>=3000)
// fused: masked per-(n,c) sums -> atomicAdd into msum (pre-zeroed).
// grid (48 lb, 8 cb, 16 n), 64x64 tiles through LDS. float4 in, f16x8 out.
// ---------------------------------------------------------------------------
__global__ __launch_bounds__(256) void k_cast(const float* __restrict__ x,
    const float* __restrict__ lengths, f16* __restrict__ xt,
    float* __restrict__ msum) {
  int lb = blockIdx.x, cb = blockIdx.y, n = blockIdx.z;
  int l0 = lb * 64, c0 = cb * 64;
  float thr = lengths[n] * (float)L_;
  int T = (int)ceilf(thr); if (T > L_) T = L_;
  __shared__ float tile[64][65];
  int tid = threadIdx.x;
  int cr = tid >> 4, l4 = (tid & 15) * 4;
  #pragma unroll
  for (int p = 0; p < 4; ++p) {
    int c = cr + p * 16;
    int l = l0 + l4;
    float4 v = make_float4(0.f, 0.f, 0.f, 0.f);
    if (l < L_) v = *(const float4*)(x + ((size_t)(n * C_ + c0 + c)) * L_ + l);
    tile[c][l4 + 0] = v.x;
    tile[c][l4 + 1] = v.y;
    tile[c][l4 + 2] = v.z;
    tile[c][l4 + 3] = v.w;
    // masked partial sum for the global-stats mean
    float part = 0.f;
    if (l     < T) part += v.x;
    if (l + 1 < T) part += v.y;
    if (l + 2 < T) part += v.z;
    if (l + 3 < T) part += v.w;
    #pragma unroll
    for (int off = 8; off; off >>= 1) part += __shfl_down(part, off, 64);
    if ((tid & 15) == 0) atomicAdd(&msum[n * C_ + c0 + c], part);
  }
  __syncthreads();
  {
    int c16 = tid & 7, lr = tid >> 3;
    #pragma unroll
    for (int p = 0; p < 2; ++p) {
      int l_loc = lr + p * 32;
      f16x8 o;
      #pragma unroll
      for (int j = 0; j < 8; ++j) o[j] = (f16)tile[c16 * 8 + j][l_loc];
      *(f16x8*)(xt + ((size_t)n * LP_ + l0 + l_loc) * C_ + c0 + c16 * 8) = o;
    }
  }
}

// ---------------------------------------------------------------------------
// k_prep2: blocks 0-15: mean/std from msum -> dba; block 0 also BN fold.
//          blocks 16-23: weight casts W1x->W1h, W2->W2h (f16).
// ---------------------------------------------------------------------------
__global__ __launch_bounds__(256) void k_prep2(const float* __restrict__ W1,
    const float* __restrict__ b1, const float* __restrict__ gamma,
    const float* __restrict__ beta, const float* __restrict__ bmean,
    const float* __restrict__ bvar, const float* __restrict__ W2,
    const float* __restrict__ lengths, const float* __restrict__ msum,
    float* __restrict__ dba, float* __restrict__ scale, float* __restrict__ shift,
    f16* __restrict__ W1h, f16* __restrict__ W2h) {
  int b = blockIdx.x;
  int tid = threadIdx.x;
  if (b < N_) {
    int n = b;
    float thr = lengths[n] * (float)L_;
    int T = (int)ceilf(thr); if (T > L_) T = L_;
    float invT = 1.f / (float)T;
    __shared__ float sm[C_], ss[C_];
    for (int c = tid; c < C_; c += 256) {
      float mean = msum[n * C_ + c] * invT;
      sm[c] = mean;
      ss[c] = sqrtf(fmaxf(mean - mean * mean, 1e-12f));
    }
    __syncthreads();
    int wv = tid >> 6, ln = tid & 63;
    for (int a = wv; a < A_; a += 4) {
      const float* wm = W1 + (size_t)a * (3 * C_) + C_;   // mean cols, then std cols
      float acc = 0.f;
      for (int c = ln; c < C_; c += 64) acc += wm[c] * sm[c] + wm[C_ + c] * ss[c];
      #pragma unroll
      for (int off = 32; off; off >>= 1) acc += __shfl_down(acc, off, 64);
      if (ln == 0) dba[n * A_ + a] = acc + b1[a];
    }
    if (n == 0 && tid < A_) {
      float sc = gamma[tid] * rsqrtf(bvar[tid] + 1e-5f);
      scale[tid] = sc;
      shift[tid] = beta[tid] - bmean[tid] * sc;
    }
  } else {
    int part = b - N_;                 // 0..7
    for (int i = tid; i < 8192; i += 256) {
      int idx = part * 8192 + i;
      int a = idx >> 9, c = idx & 511;
      W1h[idx] = (f16)W1[(size_t)a * (3 * C_) + c];  // x-columns only
      W2h[idx] = (f16)W2[idx];                       // [512][128] contiguous
    }
  }
}

// ---------------------------------------------------------------------------
// k_tdnn_f: MFMA GEMM1 from pre-transposed xt (all b128 staging):
//   ht[n][l][a] = tanh(bn(relu(W1h @ xt^T + dba)))
// grid (48 ltiles, 16 n) = 768 blocks (~3/CU), 4 waves in 2x2 (a-half, l-half)
// BM=128(a) BN=64(l) BK=64(c); LDS (128+64)x72 f16 = 27.6 KB
// ---------------------------------------------------------------------------
__global__ __launch_bounds__(256) void k_tdnn_f(const f16* __restrict__ xt,
    const f16* __restrict__ W1h, const float* __restrict__ dba,
    const float* __restrict__ scale, const float* __restrict__ shift,
    const float* __restrict__ lengths, f16* __restrict__ ht) {
  int lt0 = blockIdx.x * 64;
  int n   = blockIdx.y;
  float thr = lengths[n] * (float)L_;
  int T = (int)ceilf(thr); if (T > L_) T = L_;
  if (lt0 >= T) return;            // fully masked downstream, never read

  __shared__ __align__(16) f16 w1s[128][72];
  __shared__ __align__(16) f16 xts[64][72];
  int tid = threadIdx.x;
  int wid = tid >> 6, lane = tid & 63;
  int wr = wid >> 1, wc = wid & 1;   // wave a-half, l-half
  int fr = lane & 15, fq = lane >> 4;

  f32x4 acc[4][2];
  #pragma unroll
  for (int mi = 0; mi < 4; ++mi)
    #pragma unroll
    for (int ni = 0; ni < 2; ++ni) { f32x4 z = {0.f,0.f,0.f,0.f}; acc[mi][ni] = z; }

  int xrow = tid >> 2, xch = tid & 3;        // xts: 4 thr/row, 2 chunks each
  int wrow = tid >> 1, wch = (tid & 1) * 4;  // w1s: 2 thr/row, 4 chunks each
  const f16* xtb = xt + ((size_t)n * LP_ + lt0 + xrow) * C_;

  for (int c0 = 0; c0 < C_; c0 += 64) {
    __syncthreads();
    *(f16x8*)&xts[xrow][xch * 8]       = *(const f16x8*)(xtb + c0 + xch * 8);
    *(f16x8*)&xts[xrow][(xch + 4) * 8] = *(const f16x8*)(xtb + c0 + (xch + 4) * 8);
    #pragma unroll
    for (int q = 0; q < 4; ++q)
      *(f16x8*)&w1s[wrow][(wch + q) * 8] =
          *(const f16x8*)(W1h + (size_t)wrow * C_ + c0 + (wch + q) * 8);
    __syncthreads();
    #pragma unroll
    for (int ks = 0; ks < 2; ++ks) {
      f16x8 af[4];
      #pragma unroll
      for (int mi = 0; mi < 4; ++mi)
        af[mi] = *(const f16x8*)&w1s[wr * 64 + mi * 16 + fr][ks * 32 + fq * 8];
      #pragma unroll
      for (int ni = 0; ni < 2; ++ni) {
        f16x8 bfv = *(const f16x8*)&xts[wc * 32 + ni * 16 + fr][ks * 32 + fq * 8];
        #pragma unroll
        for (int mi = 0; mi < 4; ++mi)
          acc[mi][ni] = __builtin_amdgcn_mfma_f32_16x16x32_f16(af[mi], bfv, acc[mi][ni], 0, 0, 0);
      }
    }
  }
  // epilogue: D layout col(lane&15)=l, row((lane>>4)*4+reg)=a
  #pragma unroll
  for (int mi = 0; mi < 4; ++mi) {
    int a0 = wr * 64 + mi * 16 + fq * 4;
    f32x4 dbv = *(const f32x4*)(dba + n * A_ + a0);
    f32x4 scv = *(const f32x4*)(scale + a0);
    f32x4 shv = *(const f32x4*)(shift + a0);
    #pragma unroll
    for (int ni = 0; ni < 2; ++ni) {
      int l = lt0 + wc * 32 + ni * 16 + fr;
      f16x4 pack;
      #pragma unroll
      for (int r = 0; r < 4; ++r) {
        float v = acc[mi][ni][r] + dbv[r];
        v = fmaxf(v, 0.f) * scv[r] + shv[r];
        pack[r] = (f16)tanhf(v);
      }
      *(f16x4*)(ht + ((size_t)n * LP_ + l) * A_ + a0) = pack;
    }
  }
}

// ---------------------------------------------------------------------------
// k_attn2: MFMA GEMM2 + two-pass tile softmax via LDS score round-trip.
// grid (8 cb, 16 n, 8 seg) = 1024 blocks, 4 waves; wave owns 16 c.
// Scores go through the hts LDS region (reused after the MFMA phase), so
// pass-2 lanes own 8 CONSECUTIVE l -> x gathered as coalesced float4s.
// ---------------------------------------------------------------------------
__global__ __launch_bounds__(256) void k_attn2(const f16* __restrict__ ht,
    const float* __restrict__ x, const f16* __restrict__ W2h,
    const float* __restrict__ b2, const float* __restrict__ lengths,
    float* __restrict__ pm, float* __restrict__ ps, float* __restrict__ pt) {
  int cb = blockIdx.x * 64;
  int n  = blockIdx.y;
  int seg = blockIdx.z;
  __shared__ __align__(16) unsigned char smem[34816];   // hts[128][136] f16
  f16* hts = (f16*)smem;
  int tid = threadIdx.x, wid = tid >> 6, lane = tid & 63;
  int fr = lane & 15, fq = lane >> 4;
  float* sw = (float*)smem + (size_t)wid * 2112;        // per-wave [16][132] fp32

  // A-fragments of W2 (const per block): c = cb + wid*16 + fr, k = kk*32+fq*8
  f16x8 af[4];
  #pragma unroll
  for (int kk = 0; kk < 4; ++kk)
    af[kk] = *(const f16x8*)(W2h + (size_t)(cb + wid * 16 + fr) * A_ + kk * 32 + fq * 8);

  float thr = lengths[n] * (float)L_;
  int T = (int)ceilf(thr); if (T > L_) T = L_;
  int cme = cb + wid * 16 + fq * 4;          // this lane's 4 c rows (both passes)
  f32x4 b2v = *(const f32x4*)(b2 + cme);
  const float* xrow[4];
  #pragma unroll
  for (int r = 0; r < 4; ++r) xrow[r] = x + ((size_t)n * C_ + cme + r) * L_;
  float m[4], s[4], t[4];
  #pragma unroll
  for (int r = 0; r < 4; ++r) { m[r] = -1e30f; s[r] = 0.f; t[r] = 0.f; }

  int lbeg = seg * 384;
  int lend = (lbeg + 384 < L_) ? lbeg + 384 : L_;
  int sc16 = tid & 15, sr = tid >> 4;
  for (int l0 = lbeg; l0 < lend; l0 += 128) {
    if (l0 >= T) break;                       // uniform per block
    __syncthreads();                          // protect prev-iter sw reads
    #pragma unroll
    for (int p = 0; p < 8; ++p) {
      int r = sr + p * 16;
      *(f16x8*)&hts[(size_t)r * 136 + sc16 * 8] =
          *(const f16x8*)(ht + ((size_t)n * LP_ + l0 + r) * A_ + sc16 * 8);
    }
    __syncthreads();
    // pass 1: MFMA -> raw scores in regs
    f32x4 arr[8];
    #pragma unroll
    for (int ni = 0; ni < 8; ++ni) {
      f32x4 acc = {0.f, 0.f, 0.f, 0.f};
      #pragma unroll
      for (int kk = 0; kk < 4; ++kk) {
        f16x8 bfv = *(const f16x8*)&hts[(size_t)(ni * 16 + fr) * 136 + kk * 32 + fq * 8];
        acc = __builtin_amdgcn_mfma_f32_16x16x32_f16(af[kk], bfv, acc, 0, 0, 0);
      }
      arr[ni] = acc;
    }
    __syncthreads();                          // all waves done reading hts
    #pragma unroll
    for (int ni = 0; ni < 8; ++ni)
      #pragma unroll
      for (int r = 0; r < 4; ++r)
        sw[(fq * 4 + r) * 132 + ni * 16 + fr] = arr[ni][r] + b2v[r];
    __syncthreads();
    // pass 2: lane owns l = l0 + fr*8 .. +7 for its same 4 c rows
    #pragma unroll
    for (int r = 0; r < 4; ++r) {
      float4 sv0 = *(const float4*)&sw[(fq * 4 + r) * 132 + fr * 8];
      float4 sv1 = *(const float4*)&sw[(fq * 4 + r) * 132 + fr * 8 + 4];
      int lb = l0 + fr * 8;
      float4 xv0 = (lb     < L_) ? *(const float4*)(xrow[r] + lb)     : make_float4(0,0,0,0);
      float4 xv1 = (lb + 4 < L_) ? *(const float4*)(xrow[r] + lb + 4) : make_float4(0,0,0,0);
      float sc[8] = {sv0.x, sv0.y, sv0.z, sv0.w, sv1.x, sv1.y, sv1.z, sv1.w};
      float xvv[8] = {xv0.x, xv0.y, xv0.z, xv0.w, xv1.x, xv1.y, xv1.z, xv1.w};
      float tmax = -1e30f;
      #pragma unroll
      for (int j = 0; j < 8; ++j) tmax = fmaxf(tmax, (lb + j < T) ? sc[j] : -1e30f);
      float mn = fmaxf(m[r], tmax);
      float resc = __expf(m[r] - mn);
      s[r] *= resc; t[r] *= resc; m[r] = mn;
      #pragma unroll
      for (int j = 0; j < 8; ++j) {
        float w = (lb + j < T) ? __expf(sc[j] - mn) : 0.f;
        s[r] += w;
        t[r] += w * xvv[j];
      }
    }
  }
  // reduce across the 16 fr-lanes of each row group (within the wave)
  #pragma unroll
  for (int off = 8; off; off >>= 1) {
    #pragma unroll
    for (int r = 0; r < 4; ++r) {
      float om = __shfl_xor(m[r], off, 64);
      float os = __shfl_xor(s[r], off, 64);
      float ot = __shfl_xor(t[r], off, 64);
      float mn = fmaxf(m[r], om);
      float e1 = __expf(m[r] - mn), e2 = __expf(om - mn);
      s[r] = s[r] * e1 + os * e2;
      t[r] = t[r] * e1 + ot * e2;
      m[r] = mn;
    }
  }
  if (fr == 0) {
    #pragma unroll
    for (int r = 0; r < 4; ++r) {
      size_t idx = ((size_t)n * SEG_ + seg) * C_ + cme + r;
      pm[idx] = m[r]; ps[idx] = s[r]; pt[idx] = t[r];
    }
  }
}

// ---------------------------------------------------------------------------
// k_comb: combine the 8 l-segments, emit mean and std (shared by both paths)
// ---------------------------------------------------------------------------
__global__ __launch_bounds__(256) void k_comb(const float* __restrict__ pm,
    const float* __restrict__ ps, const float* __restrict__ pt,
    float* __restrict__ out) {
  int idx = blockIdx.x * 256 + threadIdx.x;
  if (idx >= N_ * C_) return;
  int n = idx >> 9, c = idx & 511;
  float mn = -1e30f;
  #pragma unroll
  for (int g = 0; g < SEG_; ++g) mn = fmaxf(mn, pm[((size_t)n * SEG_ + g) * C_ + c]);
  float S = 0.f, Tt = 0.f;
  #pragma unroll
  for (int g = 0; g < SEG_; ++g) {
    size_t i = ((size_t)n * SEG_ + g) * C_ + c;
    float e = __expf(pm[i] - mn);
    S  += ps[i] * e;
    Tt += pt[i] * e;
  }
  float mean = Tt / S;
  out[n * 1024 + c]       = mean;
  out[n * 1024 + 512 + c] = sqrtf(fmaxf(mean - mean * mean, 1e-12f));
}

// ===========================================================================
// FALLBACK PATH (round-6 proven kernels, used when ws_size is small)
// ===========================================================================
__global__ __launch_bounds__(256) void k_stats(const float* __restrict__ x,
                                               const float* __restrict__ lengths,
                                               float* __restrict__ mg,
                                               float* __restrict__ sg) {
  int n = blockIdx.x >> 9;
  float thr = lengths[n] * (float)L_;
  int T = (int)ceilf(thr); if (T > L_) T = L_;
  const float4* row = (const float4*)(x + (size_t)blockIdx.x * L_);
  int tid = threadIdx.x;
  float sum = 0.f;
  int nf4 = (T + 3) >> 2;
  for (int i = tid; i < nf4; i += 256) {
    float4 v = row[i];
    int l = i * 4;
    if (l + 4 <= T) sum += (v.x + v.y) + (v.z + v.w);
    else {
      if (l     < T) sum += v.x;
      if (l + 1 < T) sum += v.y;
      if (l + 2 < T) sum += v.z;
      if (l + 3 < T) sum += v.w;
    }
  }
  #pragma unroll
  for (int off = 32; off; off >>= 1) sum += __shfl_down(sum, off, 64);
  __shared__ float red[4];
  int wv = tid >> 6, ln = tid & 63;
  if (ln == 0) red[wv] = sum;
  __syncthreads();
  if (tid == 0) {
    float tot = red[0] + red[1] + red[2] + red[3];
    float mean = tot / (float)T;
    mg[blockIdx.x] = mean;
    sg[blockIdx.x] = sqrtf(fmaxf(mean - mean * mean, 1e-12f));
  }
}

__global__ __launch_bounds__(256) void k_prep(const float* __restrict__ W1,
    const float* __restrict__ b1, const float* __restrict__ gamma,
    const float* __restrict__ beta, const float* __restrict__ bmean,
    const float* __restrict__ bvar, const float* __restrict__ W2,
    const float* __restrict__ mg, const float* __restrict__ sg,
    float* __restrict__ dba, float* __restrict__ scale, float* __restrict__ shift,
    f16* __restrict__ W1h, f16* __restrict__ W2h) {
  int n = blockIdx.x;
  __shared__ float sm[C_], ss[C_];
  int tid = threadIdx.x;
  for (int c = tid; c < C_; c += 256) { sm[c] = mg[n * C_ + c]; ss[c] = sg[n * C_ + c]; }
  __syncthreads();
  int wv = tid >> 6, ln = tid & 63;
  for (int a = wv; a < A_; a += 4) {
    const float* wm = W1 + (size_t)a * (3 * C_) + C_;
    float acc = 0.f;
    for (int c = ln; c < C_; c += 64) acc += wm[c] * sm[c] + wm[C_ + c] * ss[c];
    #pragma unroll
    for (int off = 32; off; off >>= 1) acc += __shfl_down(acc, off, 64);
    if (ln == 0) dba[n * A_ + a] = acc + b1[a];
  }
  int base = n * 4096;
  for (int i = tid; i < 4096; i += 256) {
    int idx = base + i;
    int a = idx >> 9, c = idx & 511;
    W1h[idx] = (f16)W1[(size_t)a * (3 * C_) + c];
    W2h[idx] = (f16)W2[idx];
  }
  if (n == 0 && tid < A_) {
    float sc = gamma[tid] * rsqrtf(bvar[tid] + 1e-5f);
    scale[tid] = sc;
    shift[tid] = beta[tid] - bmean[tid] * sc;
  }
}

__global__ __launch_bounds__(256) void k_tdnn(const float* __restrict__ x,
    const f16* __restrict__ W1h, const float* __restrict__ dba,
    const float* __restrict__ scale, const float* __restrict__ shift,
    const float* __restrict__ lengths, f16* __restrict__ ht) {
  int lt0 = blockIdx.x * 128;
  int n   = blockIdx.y;
  float thr = lengths[n] * (float)L_;
  int T = (int)ceilf(thr); if (T > L_) T = L_;
  if (lt0 >= T) return;

  __shared__ __align__(16) f16 w1s[128][72];
  __shared__ __align__(16) f16 xts[128][72];
  int tid = threadIdx.x;
  int wid = tid >> 6, lane = tid & 63;
  int wr = wid >> 1, wc = wid & 1;
  int fr = lane & 15, fq = lane >> 4;

  f32x4 acc[4][4];
  #pragma unroll
  for (int mi = 0; mi < 4; ++mi)
    #pragma unroll
    for (int ni = 0; ni < 4; ++ni) { f32x4 z = {0.f,0.f,0.f,0.f}; acc[mi][ni] = z; }

  int tl  = tid & 127;
  int tc8 = tid >> 7;
  bool lok = (lt0 + tl) < L_;
  const float* xbase = x + (size_t)n * C_ * L_ + lt0 + tl;
  int wrow = tid >> 3;
  int wch  = tid & 7;

  for (int c0 = 0; c0 < C_; c0 += 64) {
    __syncthreads();
    #pragma unroll
    for (int it = 0; it < 4; ++it) {
      int c8 = tc8 + it * 2;
      int cg = c0 + c8 * 8;
      f16x8 pack;
      #pragma unroll
      for (int j = 0; j < 8; ++j) {
        float v = lok ? xbase[(size_t)(cg + j) * L_] : 0.f;
        pack[j] = (f16)v;
      }
      *(f16x8*)&xts[tl][c8 * 8] = pack;
    }
    #pragma unroll
    for (int it = 0; it < 4; ++it) {
      int r = wrow + it * 32;
      *(f16x8*)&w1s[r][wch * 8] =
          *(const f16x8*)(W1h + (size_t)r * C_ + c0 + wch * 8);
    }
    __syncthreads();
    #pragma unroll
    for (int ks = 0; ks < 2; ++ks) {
      f16x8 af[4];
      #pragma unroll
      for (int mi = 0; mi < 4; ++mi)
        af[mi] = *(const f16x8*)&w1s[wr * 64 + mi * 16 + fr][ks * 32 + fq * 8];
      #pragma unroll
      for (int ni = 0; ni < 4; ++ni) {
        f16x8 bfv = *(const f16x8*)&xts[wc * 64 + ni * 16 + fr][ks * 32 + fq * 8];
        #pragma unroll
        for (int mi = 0; mi < 4; ++mi)
          acc[mi][ni] = __builtin_amdgcn_mfma_f32_16x16x32_f16(af[mi], bfv, acc[mi][ni], 0, 0, 0);
      }
    }
  }
  #pragma unroll
  for (int mi = 0; mi < 4; ++mi) {
    int a0 = wr * 64 + mi * 16 + fq * 4;
    f32x4 dbv = *(const f32x4*)(dba + n * A_ + a0);
    f32x4 scv = *(const f32x4*)(scale + a0);
    f32x4 shv = *(const f32x4*)(shift + a0);
    #pragma unroll
    for (int ni = 0; ni < 4; ++ni) {
      int l = lt0 + wc * 64 + ni * 16 + fr;
      f16x4 pack;
      #pragma unroll
      for (int r = 0; r < 4; ++r) {
        float v = acc[mi][ni][r] + dbv[r];
        v = fmaxf(v, 0.f) * scv[r] + shv[r];
        pack[r] = (f16)tanhf(v);
      }
      *(f16x4*)(ht + ((size_t)n * LP_ + l) * A_ + a0) = pack;
    }
  }
}

__global__ __launch_bounds__(256) void k_attn(const f16* __restrict__ ht,
    const float* __restrict__ x, const f16* __restrict__ W2h,
    const float* __restrict__ b2, const float* __restrict__ lengths,
    float* __restrict__ pm, float* __restrict__ ps, float* __restrict__ pt) {
  int cb = blockIdx.x * 64;
  int n  = blockIdx.y;
  int seg = blockIdx.z;
  __shared__ __align__(16) f16 hts[128][136];
  int tid = threadIdx.x, wid = tid >> 6, lane = tid & 63;
  int fr = lane & 15, fq = lane >> 4;

  f16x8 af[4];
  #pragma unroll
  for (int kk = 0; kk < 4; ++kk)
    af[kk] = *(const f16x8*)(W2h + (size_t)(cb + wid * 16 + fr) * A_ + kk * 32 + fq * 8);

  float thr = lengths[n] * (float)L_;
  int T = (int)ceilf(thr); if (T > L_) T = L_;
  int cme = cb + wid * 16 + fq * 4;
  f32x4 b2v = *(const f32x4*)(b2 + cme);
  const float* xrow[4];
  #pragma unroll
  for (int r = 0; r < 4; ++r) xrow[r] = x + ((size_t)n * C_ + cme + r) * L_;
  float m[4], s[4], t[4];
  #pragma unroll
  for (int r = 0; r < 4; ++r) { m[r] = -1e30f; s[r] = 0.f; t[r] = 0.f; }

  int lbeg = seg * 384;
  int lend = (lbeg + 384 < L_) ? lbeg + 384 : L_;
  int sc16 = tid & 15, sr = tid >> 4;
  for (int l0 = lbeg; l0 < lend; l0 += 128) {
    if (l0 >= T) break;
    __syncthreads();
    #pragma unroll
    for (int p = 0; p < 8; ++p) {
      int r = sr + p * 16;
      *(f16x8*)&hts[r][sc16 * 8] =
          *(const f16x8*)(ht + ((size_t)n * LP_ + l0 + r) * A_ + sc16 * 8);
    }
    __syncthreads();
    #pragma unroll
    for (int ni = 0; ni < 8; ++ni) {
      f32x4 acc = {0.f, 0.f, 0.f, 0.f};
      #pragma unroll
      for (int kk = 0; kk < 4; ++kk) {
        f16x8 bfv = *(const f16x8*)&hts[ni * 16 + fr][kk * 32 + fq * 8];
        acc = __builtin_amdgcn_mfma_f32_16x16x32_f16(af[kk], bfv, acc, 0, 0, 0);
      }
      int l = l0 + ni * 16 + fr;
      bool live = l < T;
      #pragma unroll
      for (int r = 0; r < 4; ++r) {
        float aval = live ? (acc[r] + b2v[r]) : -1e30f;
        float mn = fmaxf(m[r], aval);
        float eo = __expf(m[r] - mn);
        float w  = live ? __expf(aval - mn) : 0.f;
        float xv = live ? xrow[r][l] : 0.f;
        s[r] = s[r] * eo + w;
        t[r] = t[r] * eo + w * xv;
        m[r] = mn;
      }
    }
  }
  #pragma unroll
  for (int off = 8; off; off >>= 1) {
    #pragma unroll
    for (int r = 0; r < 4; ++r) {
      float om = __shfl_xor(m[r], off, 64);
      float os = __shfl_xor(s[r], off, 64);
      float ot = __shfl_xor(t[r], off, 64);
      float mn = fmaxf(m[r], om);
      float e1 = __expf(m[r] - mn), e2 = __expf(om - mn);
      s[r] = s[r] * e1 + os * e2;
      t[r] = t[r] * e1 + ot * e2;
      m[r] = mn;
    }
  }
  if (fr == 0) {
    #pragma unroll
    for (int r = 0; r < 4; ++r) {
      size_t idx = ((size_t)n * SEG_ + seg) * C_ + cme + r;
      pm[idx] = m[r]; ps[idx] = s[r]; pt[idx] = t[r];
    }
  }
}

// ---------------------------------------------------------------------------
extern "C" void kernel_launch(void* const* d_in, const int* in_sizes, int n_in,
                              void* d_out, int out_size, void* d_ws, size_t ws_size,
                              hipStream_t stream) {
  const float* x       = (const float*)d_in[0];
  const float* lengths = (const float*)d_in[1];
  const float* W1      = (const float*)d_in[2];
  const float* b1      = (const float*)d_in[3];
  const float* gamma   = (const float*)d_in[4];
  const float* beta    = (const float*)d_in[5];
  const float* bmean   = (const float*)d_in[6];
  const float* bvar    = (const float*)d_in[7];
  const float* W2      = (const float*)d_in[8];
  const float* b2      = (const float*)d_in[9];
  float* out = (float*)d_out;

  const size_t NEED_FAST = 64005120;   // ~61 MiB
  if (ws_size >= NEED_FAST) {
    char* w = (char*)d_ws;
    f16* xt    = (f16*)w;    w += (size_t)N_ * LP_ * C_ * 2;   // 50,331,648
    f16* ht    = (f16*)w;    w += (size_t)N_ * LP_ * A_ * 2;   // 12,582,912
    f16* W1h   = (f16*)w;    w += (size_t)A_ * C_ * 2;
    f16* W2h   = (f16*)w;    w += (size_t)C_ * A_ * 2;
    float* msum = (float*)w; w += (size_t)N_ * C_ * 4;
    float* dba = (float*)w;  w += (size_t)N_ * A_ * 4;
    float* scale = (float*)w; w += 512;
    float* shift = (float*)w; w += 512;
    float* pm  = (float*)w;  w += (size_t)N_ * SEG_ * C_ * 4;
    float* ps  = (float*)w;  w += (size_t)N_ * SEG_ * C_ * 4;
    float* pt  = (float*)w;

    hipMemsetAsync(msum, 0, (size_t)N_ * C_ * 4, stream);
    k_cast  <<<dim3(48, 8, N_), 256, 0, stream>>>(x, lengths, xt, msum);
    k_prep2 <<<dim3(24), 256, 0, stream>>>(W1, b1, gamma, beta, bmean, bvar, W2,
                                           lengths, msum, dba, scale, shift, W1h, W2h);
    k_tdnn_f<<<dim3(48, N_), 256, 0, stream>>>(xt, W1h, dba, scale, shift, lengths, ht);
    k_attn2 <<<dim3(8, N_, SEG_), 256, 0, stream>>>(ht, x, W2h, b2, lengths, pm, ps, pt);
    k_comb  <<<dim3(32), 256, 0, stream>>>(pm, ps, pt, out);
  } else {
    // fallback: round-6 proven path (~13.6 MB ws)
    char* w = (char*)d_ws;
    f16* ht    = (f16*)w;    w += (size_t)N_ * LP_ * A_ * 2;
    f16* W1h   = (f16*)w;    w += (size_t)A_ * C_ * 2;
    f16* W2h   = (f16*)w;    w += (size_t)C_ * A_ * 2;
    float* mg  = (float*)w;  w += (size_t)N_ * C_ * 4;
    float* sg  = (float*)w;  w += (size_t)N_ * C_ * 4;
    float* dba = (float*)w;  w += (size_t)N_ * A_ * 4;
    float* scale = (float*)w; w += 512;
    float* shift = (float*)w; w += 512;
    float* pm  = (float*)w;  w += (size_t)N_ * SEG_ * C_ * 4;
    float* ps  = (float*)w;  w += (size_t)N_ * SEG_ * C_ * 4;
    float* pt  = (float*)w;

    k_stats<<<dim3(N_ * C_), 256, 0, stream>>>(x, lengths, mg, sg);
    k_prep <<<dim3(N_), 256, 0, stream>>>(W1, b1, gamma, beta, bmean, bvar, W2,
                                          mg, sg, dba, scale, shift, W1h, W2h);
    k_tdnn <<<dim3(24, N_), 256, 0, stream>>>(x, W1h, dba, scale, shift, lengths, ht);
    k_attn <<<dim3(8, N_, SEG_), 256, 0, stream>>>(ht, x, W2h, b2, lengths, pm, ps, pt);
    k_comb <<<dim3(32), 256, 0, stream>>>(pm, ps, pt, out);
  }
}